// Round 1
// baseline (2616.480 us; speedup 1.0000x reference)
//
#include <hip/hip_runtime.h>

#define NN 40000
#define NE 640000
#define DD 128
#define K3 384
#define BM 128
#define BK 32
#define LDA 33       // padded LDS row stride for GEMM tiles
#define SV 65        // padded LDS row stride for the 128x64 epilogue half-tile
#define NTILES 313   // ceil(40000/128)

// ---------- P,Q = x @ W1a^T , x @ W1b^T  (blockIdx.y selects column block of W1) ----
__global__ __launch_bounds__(256, 4)
void pq_kernel(const float* __restrict__ x, const float* __restrict__ W1,
               float* __restrict__ P, float* __restrict__ Q)
{
    __shared__ float As[BM * LDA];
    __shared__ float Ws[DD * LDA];
    const int t = threadIdx.x;
    const int n0 = blockIdx.x * BM;
    const int off = blockIdx.y * DD;          // 0 -> P (x[dst] slot), 128 -> Q (x[src] slot)
    float* __restrict__ OUT = blockIdx.y == 0 ? P : Q;
    const int tx = t & 15, ty = t >> 4;

    float acc[8][8];
    #pragma unroll
    for (int i = 0; i < 8; ++i)
        #pragma unroll
        for (int j = 0; j < 8; ++j) acc[i][j] = 0.f;

    for (int kt = 0; kt < 4; ++kt) {
        #pragma unroll
        for (int i = 0; i < 4; ++i) {
            int idx = i * 256 + t, m = idx >> 3, c4 = idx & 7;
            int n = n0 + m; if (n >= NN) n = NN - 1;
            float4 v = *(const float4*)(x + (size_t)n * DD + kt * BK + c4 * 4);
            float* w = As + m * LDA + c4 * 4;
            w[0] = v.x; w[1] = v.y; w[2] = v.z; w[3] = v.w;
        }
        #pragma unroll
        for (int i = 0; i < 4; ++i) {
            int idx = i * 256 + t, d = idx >> 3, c4 = idx & 7;
            float4 v = *(const float4*)(W1 + (size_t)d * K3 + off + kt * BK + c4 * 4);
            float* w = Ws + d * LDA + c4 * 4;
            w[0] = v.x; w[1] = v.y; w[2] = v.z; w[3] = v.w;
        }
        __syncthreads();
        #pragma unroll 8
        for (int f = 0; f < BK; ++f) {
            float a[8], b[8];
            #pragma unroll
            for (int i = 0; i < 8; ++i) a[i] = As[(ty * 8 + i) * LDA + f];
            #pragma unroll
            for (int j = 0; j < 4; ++j) {
                b[j]     = Ws[(tx * 4 + j) * LDA + f];
                b[4 + j] = Ws[(64 + tx * 4 + j) * LDA + f];
            }
            #pragma unroll
            for (int i = 0; i < 8; ++i)
                #pragma unroll
                for (int j = 0; j < 8; ++j)
                    acc[i][j] = fmaf(a[i], b[j], acc[i][j]);
        }
        __syncthreads();
    }
    #pragma unroll
    for (int i = 0; i < 8; ++i) {
        int n = n0 + ty * 8 + i;
        if (n < NN) {
            float4 o1 = { acc[i][0], acc[i][1], acc[i][2], acc[i][3] };
            float4 o2 = { acc[i][4], acc[i][5], acc[i][6], acc[i][7] };
            *(float4*)(OUT + (size_t)n * DD + tx * 4)      = o1;
            *(float4*)(OUT + (size_t)n * DD + 64 + tx * 4) = o2;
        }
    }
}

// ---------- counting sort of edges by dst: histogram -> scan -> scatter ------------
__global__ __launch_bounds__(256)
void hist_kernel(const int* __restrict__ dst, int* __restrict__ deg)
{
    int e = blockIdx.x * 256 + threadIdx.x;
    atomicAdd(&deg[dst[e]], 1);
}

#define SCAN_CHUNK 157   // 256*157 = 40192 >= 40000
__global__ __launch_bounds__(256)
void scan_kernel(const int* __restrict__ deg, int* __restrict__ cursor)
{
    __shared__ int part[256];
    const int t = threadIdx.x;
    const int base = t * SCAN_CHUNK;
    int s = 0;
    for (int i = 0; i < SCAN_CHUNK; ++i) {
        int idx = base + i;
        if (idx < NN) s += deg[idx];
    }
    part[t] = s;
    __syncthreads();
    #pragma unroll
    for (int off = 1; off < 256; off <<= 1) {
        int v = (t >= off) ? part[t - off] : 0;
        __syncthreads();
        part[t] += v;
        __syncthreads();
    }
    int run = (t > 0) ? part[t - 1] : 0;
    for (int i = 0; i < SCAN_CHUNK; ++i) {
        int idx = base + i;
        if (idx < NN) { cursor[idx] = run; run += deg[idx]; }
    }
}

__global__ __launch_bounds__(256)
void scatter_kernel(const int* __restrict__ src, const int* __restrict__ dst,
                    int* __restrict__ cursor, int* __restrict__ eid_s,
                    int* __restrict__ dst_s, int* __restrict__ src_s)
{
    int e = blockIdx.x * 256 + threadIdx.x;
    int d = dst[e];
    int pos = atomicAdd(&cursor[d], 1);
    eid_s[pos] = e;
    dst_s[pos] = d;
    src_s[pos] = src[e];
}

// ---------- R = h[sorted] @ W1c^T; segmented-reduce relu(R+P[dst]+Q[src]) -> m_node -
// Edges arrive sorted by dst, so each 128-edge tile holds contiguous runs of equal
// dst. Epilogue: stage relu(acc+P+Q) in LDS (two 64-col halves), per-column run-sum,
// one coalesced 64-lane atomicAdd per run per 32-row quarter.
__global__ __launch_bounds__(256, 4)
void r_gemm_seg(const float* __restrict__ h, const float* __restrict__ W1,
                const float* __restrict__ P, const float* __restrict__ Q,
                const int* __restrict__ eid_s, const int* __restrict__ src_s,
                const int* __restrict__ dst_s, float* __restrict__ m_node)
{
    __shared__ float smem[BM * LDA + DD * LDA];   // GEMM: As|Ws; epilogue: V[128][SV]
    __shared__ int eidS[BM], dstS[BM], srcS[BM];

    const int t = threadIdx.x;
    const int e0 = blockIdx.x * BM;
    if (t < BM) { eidS[t] = eid_s[e0 + t]; dstS[t] = dst_s[e0 + t]; srcS[t] = src_s[e0 + t]; }
    __syncthreads();

    float* As = smem;
    float* Ws = smem + BM * LDA;
    const int tx = t & 15, ty = t >> 4;

    float acc[8][8];
    #pragma unroll
    for (int i = 0; i < 8; ++i)
        #pragma unroll
        for (int j = 0; j < 8; ++j) acc[i][j] = 0.f;

    for (int kt = 0; kt < 4; ++kt) {
        #pragma unroll
        for (int i = 0; i < 4; ++i) {
            int idx = i * 256 + t, m = idx >> 3, c4 = idx & 7;
            float4 v = *(const float4*)(h + (size_t)eidS[m] * DD + kt * BK + c4 * 4);
            float* w = As + m * LDA + c4 * 4;
            w[0] = v.x; w[1] = v.y; w[2] = v.z; w[3] = v.w;
        }
        #pragma unroll
        for (int i = 0; i < 4; ++i) {
            int idx = i * 256 + t, d = idx >> 3, c4 = idx & 7;
            float4 v = *(const float4*)(W1 + (size_t)d * K3 + 256 + kt * BK + c4 * 4);
            float* w = Ws + d * LDA + c4 * 4;
            w[0] = v.x; w[1] = v.y; w[2] = v.z; w[3] = v.w;
        }
        __syncthreads();
        #pragma unroll 8
        for (int f = 0; f < BK; ++f) {
            float a[8], b[8];
            #pragma unroll
            for (int i = 0; i < 8; ++i) a[i] = As[(ty * 8 + i) * LDA + f];
            #pragma unroll
            for (int j = 0; j < 4; ++j) {
                b[j]     = Ws[(tx * 4 + j) * LDA + f];
                b[4 + j] = Ws[(64 + tx * 4 + j) * LDA + f];
            }
            #pragma unroll
            for (int i = 0; i < 8; ++i)
                #pragma unroll
                for (int j = 0; j < 8; ++j)
                    acc[i][j] = fmaf(a[i], b[j], acc[i][j]);
        }
        __syncthreads();
    }

    float* V = smem;   // alias: GEMM tiles dead after last sync

    // ---- half 0: cols 0..63 ----
    #pragma unroll
    for (int i = 0; i < 8; ++i) {
        int m = ty * 8 + i;
        float4 p = *(const float4*)(P + (size_t)dstS[m] * DD + tx * 4);
        float4 q = *(const float4*)(Q + (size_t)srcS[m] * DD + tx * 4);
        float* w = V + m * SV + tx * 4;
        w[0] = fmaxf(acc[i][0] + p.x + q.x, 0.f);
        w[1] = fmaxf(acc[i][1] + p.y + q.y, 0.f);
        w[2] = fmaxf(acc[i][2] + p.z + q.z, 0.f);
        w[3] = fmaxf(acc[i][3] + p.w + q.w, 0.f);
    }
    __syncthreads();
    {
        const int c = t & 63, qu = t >> 6, m0 = qu * 32;
        float sum = 0.f;
        for (int m = m0; m < m0 + 32; ++m) {
            sum += V[m * SV + c];
            if (m == m0 + 31 || dstS[m + 1] != dstS[m]) {   // wave-uniform
                atomicAdd(m_node + (size_t)dstS[m] * DD + c, sum);
                sum = 0.f;
            }
        }
    }
    __syncthreads();

    // ---- half 1: cols 64..127 ----
    #pragma unroll
    for (int i = 0; i < 8; ++i) {
        int m = ty * 8 + i;
        float4 p = *(const float4*)(P + (size_t)dstS[m] * DD + 64 + tx * 4);
        float4 q = *(const float4*)(Q + (size_t)srcS[m] * DD + 64 + tx * 4);
        float* w = V + m * SV + tx * 4;
        w[0] = fmaxf(acc[i][4] + p.x + q.x, 0.f);
        w[1] = fmaxf(acc[i][5] + p.y + q.y, 0.f);
        w[2] = fmaxf(acc[i][6] + p.z + q.z, 0.f);
        w[3] = fmaxf(acc[i][7] + p.w + q.w, 0.f);
    }
    __syncthreads();
    {
        const int c = t & 63, qu = t >> 6, m0 = qu * 32;
        float sum = 0.f;
        for (int m = m0; m < m0 + 32; ++m) {
            sum += V[m * SV + c];
            if (m == m0 + 31 || dstS[m + 1] != dstS[m]) {
                atomicAdd(m_node + (size_t)dstS[m] * DD + 64 + c, sum);
                sum = 0.f;
            }
        }
    }
}

// ---------- T = m_node @ W2^T ------------------------------------------------------
__global__ __launch_bounds__(256, 4)
void t_kernel(const float* __restrict__ m_node, const float* __restrict__ W2,
              float* __restrict__ T)
{
    __shared__ float As[BM * LDA];
    __shared__ float Ws[DD * LDA];
    const int t = threadIdx.x;
    const int n0 = blockIdx.x * BM;
    const int tx = t & 15, ty = t >> 4;

    float acc[8][8];
    #pragma unroll
    for (int i = 0; i < 8; ++i)
        #pragma unroll
        for (int j = 0; j < 8; ++j) acc[i][j] = 0.f;

    for (int kt = 0; kt < 4; ++kt) {
        #pragma unroll
        for (int i = 0; i < 4; ++i) {
            int idx = i * 256 + t, m = idx >> 3, c4 = idx & 7;
            int n = n0 + m; if (n >= NN) n = NN - 1;
            float4 v = *(const float4*)(m_node + (size_t)n * DD + kt * BK + c4 * 4);
            float* w = As + m * LDA + c4 * 4;
            w[0] = v.x; w[1] = v.y; w[2] = v.z; w[3] = v.w;
        }
        #pragma unroll
        for (int i = 0; i < 4; ++i) {
            int idx = i * 256 + t, d = idx >> 3, c4 = idx & 7;
            float4 v = *(const float4*)(W2 + (size_t)d * DD + kt * BK + c4 * 4);
            float* w = Ws + d * LDA + c4 * 4;
            w[0] = v.x; w[1] = v.y; w[2] = v.z; w[3] = v.w;
        }
        __syncthreads();
        #pragma unroll 8
        for (int f = 0; f < BK; ++f) {
            float a[8], b[8];
            #pragma unroll
            for (int i = 0; i < 8; ++i) a[i] = As[(ty * 8 + i) * LDA + f];
            #pragma unroll
            for (int j = 0; j < 4; ++j) {
                b[j]     = Ws[(tx * 4 + j) * LDA + f];
                b[4 + j] = Ws[(64 + tx * 4 + j) * LDA + f];
            }
            #pragma unroll
            for (int i = 0; i < 8; ++i)
                #pragma unroll
                for (int j = 0; j < 8; ++j)
                    acc[i][j] = fmaf(a[i], b[j], acc[i][j]);
        }
        __syncthreads();
    }
    #pragma unroll
    for (int i = 0; i < 8; ++i) {
        int n = n0 + ty * 8 + i;
        if (n < NN) {
            float4 o1 = { acc[i][0], acc[i][1], acc[i][2], acc[i][3] };
            float4 o2 = { acc[i][4], acc[i][5], acc[i][6], acc[i][7] };
            *(float4*)(T + (size_t)n * DD + tx * 4)      = o1;
            *(float4*)(T + (size_t)n * DD + 64 + tx * 4) = o2;
        }
    }
}

// ---------- out = relu(LN(T[src] * snorm_n)) — 32 lanes per edge row ---------------
__global__ __launch_bounds__(256, 8)
void final_kernel(const float* __restrict__ T, const float* __restrict__ snorm_n,
                  const float* __restrict__ gamma, const float* __restrict__ beta,
                  const int* __restrict__ src, float* __restrict__ out)
{
    const int t = threadIdx.x;
    const int l = t & 31;
    const int e = blockIdx.x * 8 + (t >> 5);
    const int s = src[e];
    const float sc = snorm_n[e];
    float4 v = *(const float4*)(T + (size_t)s * DD + l * 4);
    v.x *= sc; v.y *= sc; v.z *= sc; v.w *= sc;
    float sum = v.x + v.y + v.z + v.w;
    float sq  = v.x * v.x + v.y * v.y + v.z * v.z + v.w * v.w;
    #pragma unroll
    for (int off = 1; off < 32; off <<= 1) {
        sum += __shfl_xor(sum, off);
        sq  += __shfl_xor(sq,  off);
    }
    float mu  = sum * (1.f / 128.f);
    float var = sq * (1.f / 128.f) - mu * mu;
    float rs  = rsqrtf(var + 1e-5f);
    float4 g = *(const float4*)(gamma + l * 4);
    float4 b = *(const float4*)(beta  + l * 4);
    float4 o;
    o.x = fmaxf((v.x - mu) * rs * g.x + b.x, 0.f);
    o.y = fmaxf((v.y - mu) * rs * g.y + b.y, 0.f);
    o.z = fmaxf((v.z - mu) * rs * g.z + b.z, 0.f);
    o.w = fmaxf((v.w - mu) * rs * g.w + b.w, 0.f);
    *(float4*)(out + (size_t)e * DD + l * 4) = o;
}

extern "C" void kernel_launch(void* const* d_in, const int* in_sizes, int n_in,
                              void* d_out, int out_size, void* d_ws, size_t ws_size,
                              hipStream_t stream) {
    const float* x       = (const float*)d_in[0];
    const float* h       = (const float*)d_in[1];
    const float* snorm_n = (const float*)d_in[2];
    const float* W1      = (const float*)d_in[4];
    const float* W2      = (const float*)d_in[5];
    const float* gamma   = (const float*)d_in[6];
    const float* beta    = (const float*)d_in[7];
    const int*   src     = (const int*)d_in[8];
    const int*   dst     = (const int*)d_in[9];
    float* out = (float*)d_out;

    const size_t NF = (size_t)NN * DD;       // 5.12M floats per node-array
    float* m_node = (float*)d_ws;            // [0 .. NF)
    float* P      = m_node + NF;
    float* Q      = m_node + 2 * NF;
    float* T      = m_node + 3 * NF;         // 81.9 MB
    int*   deg    = (int*)(m_node + 4 * NF); // NN ints
    int*   cursor = deg + NN;                // NN ints
    int*   eid_s  = cursor + NN;             // NE ints
    int*   dst_s  = eid_s + NE;              // NE ints
    int*   src_s  = dst_s + NE;              // NE ints  (total ws ~= 90 MB)

    hipMemsetAsync(m_node, 0, NF * sizeof(float), stream);
    hipMemsetAsync(deg, 0, NN * sizeof(int), stream);

    hist_kernel<<<NE / 256, 256, 0, stream>>>(dst, deg);
    scan_kernel<<<1, 256, 0, stream>>>(deg, cursor);
    scatter_kernel<<<NE / 256, 256, 0, stream>>>(src, dst, cursor, eid_s, dst_s, src_s);

    pq_kernel<<<dim3(NTILES, 2), 256, 0, stream>>>(x, W1, P, Q);
    r_gemm_seg<<<NE / BM, 256, 0, stream>>>(h, W1, P, Q, eid_s, src_s, dst_s, m_node);
    t_kernel<<<NTILES, 256, 0, stream>>>(m_node, W2, T);
    final_kernel<<<NE / 8, 256, 0, stream>>>(T, snorm_n, gamma, beta, src, out);
}

// Round 2
// 1467.066 us; speedup vs baseline: 1.7835x; 1.7835x over previous
//
#include <hip/hip_runtime.h>

#define NN 40000
#define NE 640000
#define DD 128
#define K3 384
#define BM 128
#define BK 32
#define LDA 33       // padded LDS row stride for GEMM tiles
#define SV 65        // padded LDS row stride for the 128x64 epilogue half-tile
#define NTILES 313   // ceil(40000/128)

// ---------- P,Q = x @ W1a^T , x @ W1b^T  (blockIdx.y selects column block of W1) ----
__global__ __launch_bounds__(256, 4)
void pq_kernel(const float* __restrict__ x, const float* __restrict__ W1,
               float* __restrict__ P, float* __restrict__ Q)
{
    __shared__ float As[BM * LDA];
    __shared__ float Ws[DD * LDA];
    const int t = threadIdx.x;
    const int n0 = blockIdx.x * BM;
    const int off = blockIdx.y * DD;          // 0 -> P (x[dst] slot), 128 -> Q (x[src] slot)
    float* __restrict__ OUT = blockIdx.y == 0 ? P : Q;
    const int tx = t & 15, ty = t >> 4;

    float acc[8][8];
    #pragma unroll
    for (int i = 0; i < 8; ++i)
        #pragma unroll
        for (int j = 0; j < 8; ++j) acc[i][j] = 0.f;

    for (int kt = 0; kt < 4; ++kt) {
        #pragma unroll
        for (int i = 0; i < 4; ++i) {
            int idx = i * 256 + t, m = idx >> 3, c4 = idx & 7;
            int n = n0 + m; if (n >= NN) n = NN - 1;
            float4 v = *(const float4*)(x + (size_t)n * DD + kt * BK + c4 * 4);
            float* w = As + m * LDA + c4 * 4;
            w[0] = v.x; w[1] = v.y; w[2] = v.z; w[3] = v.w;
        }
        #pragma unroll
        for (int i = 0; i < 4; ++i) {
            int idx = i * 256 + t, d = idx >> 3, c4 = idx & 7;
            float4 v = *(const float4*)(W1 + (size_t)d * K3 + off + kt * BK + c4 * 4);
            float* w = Ws + d * LDA + c4 * 4;
            w[0] = v.x; w[1] = v.y; w[2] = v.z; w[3] = v.w;
        }
        __syncthreads();
        #pragma unroll 8
        for (int f = 0; f < BK; ++f) {
            float a[8], b[8];
            #pragma unroll
            for (int i = 0; i < 8; ++i) a[i] = As[(ty * 8 + i) * LDA + f];
            #pragma unroll
            for (int j = 0; j < 4; ++j) {
                b[j]     = Ws[(tx * 4 + j) * LDA + f];
                b[4 + j] = Ws[(64 + tx * 4 + j) * LDA + f];
            }
            #pragma unroll
            for (int i = 0; i < 8; ++i)
                #pragma unroll
                for (int j = 0; j < 8; ++j)
                    acc[i][j] = fmaf(a[i], b[j], acc[i][j]);
        }
        __syncthreads();
    }
    #pragma unroll
    for (int i = 0; i < 8; ++i) {
        int n = n0 + ty * 8 + i;
        if (n < NN) {
            float4 o1 = { acc[i][0], acc[i][1], acc[i][2], acc[i][3] };
            float4 o2 = { acc[i][4], acc[i][5], acc[i][6], acc[i][7] };
            *(float4*)(OUT + (size_t)n * DD + tx * 4)      = o1;
            *(float4*)(OUT + (size_t)n * DD + 64 + tx * 4) = o2;
        }
    }
}

// ---------- counting sort of edges by dst: histogram -> scan -> scatter ------------
__global__ __launch_bounds__(256)
void hist_kernel(const int* __restrict__ dst, int* __restrict__ deg)
{
    int e = blockIdx.x * 256 + threadIdx.x;
    atomicAdd(&deg[dst[e]], 1);
}

#define SCAN_CHUNK 157   // 256*157 = 40192 >= 40000
__global__ __launch_bounds__(256)
void scan_kernel(const int* __restrict__ deg, int* __restrict__ cursor)
{
    __shared__ int part[256];
    const int t = threadIdx.x;
    const int base = t * SCAN_CHUNK;
    int s = 0;
    for (int i = 0; i < SCAN_CHUNK; ++i) {
        int idx = base + i;
        if (idx < NN) s += deg[idx];
    }
    part[t] = s;
    __syncthreads();
    #pragma unroll
    for (int off = 1; off < 256; off <<= 1) {
        int v = (t >= off) ? part[t - off] : 0;
        __syncthreads();
        part[t] += v;
        __syncthreads();
    }
    int run = (t > 0) ? part[t - 1] : 0;
    for (int i = 0; i < SCAN_CHUNK; ++i) {
        int idx = base + i;
        if (idx < NN) { cursor[idx] = run; run += deg[idx]; }
    }
}

__global__ __launch_bounds__(256)
void scatter_kernel(const int* __restrict__ src, const int* __restrict__ dst,
                    int* __restrict__ cursor, int* __restrict__ eid_s,
                    int* __restrict__ dst_s, int* __restrict__ src_s)
{
    int e = blockIdx.x * 256 + threadIdx.x;
    int d = dst[e];
    int pos = atomicAdd(&cursor[d], 1);
    eid_s[pos] = e;
    dst_s[pos] = d;
    src_s[pos] = src[e];
}

// ---------- R = h[sorted] @ W1c^T; segmented-reduce relu(R+P[dst]+Q[src]) -> m_node -
// Reg-prefetch double-buffered GEMM (hide h-gather latency under FMA phase).
// Epilogue: one wave serial-scans each staged 128x64 half; runs interior to the
// block -> plain coalesced store (exclusive owner); block-boundary runs -> atomicAdd.
__global__ __launch_bounds__(256, 4)
void r_gemm_seg(const float* __restrict__ h, const float* __restrict__ W1,
                const float* __restrict__ P, const float* __restrict__ Q,
                const int* __restrict__ eid_s, const int* __restrict__ src_s,
                const int* __restrict__ dst_s, float* __restrict__ m_node)
{
    __shared__ float smem[BM * LDA + DD * LDA];   // GEMM: As|Ws; epilogue: V[128][SV]
    __shared__ int eidS[BM], dstS[BM], srcS[BM];

    const int t = threadIdx.x;
    const int e0 = blockIdx.x * BM;
    if (t < BM) { eidS[t] = eid_s[e0 + t]; dstS[t] = dst_s[e0 + t]; srcS[t] = src_s[e0 + t]; }
    __syncthreads();

    float* As = smem;
    float* Ws = smem + BM * LDA;
    const int tx = t & 15, ty = t >> 4;

    // per-thread staging coordinates (4 chunks of 16B each for h-tile and W1-tile)
    int hoff[4];   // element offset of this thread's h chunk base (row*DD + c4*4)
    #pragma unroll
    for (int i = 0; i < 4; ++i) {
        int idx = i * 256 + t, m = idx >> 3, c4 = idx & 7;
        hoff[i] = eidS[m] * DD + c4 * 4;
    }

    float acc[8][8];
    #pragma unroll
    for (int i = 0; i < 8; ++i)
        #pragma unroll
        for (int j = 0; j < 8; ++j) acc[i][j] = 0.f;

    // prefetch kt=0 into registers
    float4 ha[4], wa[4];
    #pragma unroll
    for (int i = 0; i < 4; ++i) {
        int idx = i * 256 + t, d = idx >> 3, c4 = idx & 7;
        ha[i] = *(const float4*)(h + hoff[i]);
        wa[i] = *(const float4*)(W1 + (size_t)d * K3 + 256 + c4 * 4);
    }

    for (int kt = 0; kt < 4; ++kt) {
        // write current tile regs -> LDS
        #pragma unroll
        for (int i = 0; i < 4; ++i) {
            int idx = i * 256 + t, m = idx >> 3, c4 = idx & 7;
            float* w  = As + m * LDA + c4 * 4;
            w[0] = ha[i].x; w[1] = ha[i].y; w[2] = ha[i].z; w[3] = ha[i].w;
            float* w2 = Ws + m * LDA + c4 * 4;
            w2[0] = wa[i].x; w2[1] = wa[i].y; w2[2] = wa[i].z; w2[3] = wa[i].w;
        }
        __syncthreads();
        // issue next tile's loads; latency hides under the FMA phase below
        if (kt < 3) {
            #pragma unroll
            for (int i = 0; i < 4; ++i) {
                int idx = i * 256 + t, d = idx >> 3, c4 = idx & 7;
                ha[i] = *(const float4*)(h + hoff[i] + (kt + 1) * BK);
                wa[i] = *(const float4*)(W1 + (size_t)d * K3 + 256 + (kt + 1) * BK + c4 * 4);
            }
        }
        #pragma unroll 8
        for (int f = 0; f < BK; ++f) {
            float a[8], b[8];
            #pragma unroll
            for (int i = 0; i < 8; ++i) a[i] = As[(ty * 8 + i) * LDA + f];
            #pragma unroll
            for (int j = 0; j < 4; ++j) {
                b[j]     = Ws[(tx * 4 + j) * LDA + f];
                b[4 + j] = Ws[(64 + tx * 4 + j) * LDA + f];
            }
            #pragma unroll
            for (int i = 0; i < 8; ++i)
                #pragma unroll
                for (int j = 0; j < 8; ++j)
                    acc[i][j] = fmaf(a[i], b[j], acc[i][j]);
        }
        __syncthreads();
    }

    float* V = smem;   // alias: GEMM tiles dead after last sync

    // ---- half 0: cols 0..63 ----
    #pragma unroll
    for (int i = 0; i < 8; ++i) {
        int m = ty * 8 + i;
        float4 p = *(const float4*)(P + (size_t)dstS[m] * DD + tx * 4);
        float4 q = *(const float4*)(Q + (size_t)srcS[m] * DD + tx * 4);
        float* w = V + m * SV + tx * 4;
        w[0] = fmaxf(acc[i][0] + p.x + q.x, 0.f);
        w[1] = fmaxf(acc[i][1] + p.y + q.y, 0.f);
        w[2] = fmaxf(acc[i][2] + p.z + q.z, 0.f);
        w[3] = fmaxf(acc[i][3] + p.w + q.w, 0.f);
    }
    __syncthreads();
    if (t < 64) {
        const int c = t;
        float sum = 0.f;
        int runstart = 0;
        for (int m = 0; m < BM; ++m) {
            sum += V[m * SV + c];
            if (m == BM - 1 || dstS[m + 1] != dstS[m]) {        // wave-uniform
                float* p = m_node + (size_t)dstS[m] * DD + c;
                if (runstart == 0 || m == BM - 1) atomicAdd(p, sum);  // may span blocks
                else *p = sum;                                        // exclusive run
                sum = 0.f; runstart = m + 1;
            }
        }
    }
    __syncthreads();

    // ---- half 1: cols 64..127 ----
    #pragma unroll
    for (int i = 0; i < 8; ++i) {
        int m = ty * 8 + i;
        float4 p = *(const float4*)(P + (size_t)dstS[m] * DD + 64 + tx * 4);
        float4 q = *(const float4*)(Q + (size_t)srcS[m] * DD + 64 + tx * 4);
        float* w = V + m * SV + tx * 4;
        w[0] = fmaxf(acc[i][4] + p.x + q.x, 0.f);
        w[1] = fmaxf(acc[i][5] + p.y + q.y, 0.f);
        w[2] = fmaxf(acc[i][6] + p.z + q.z, 0.f);
        w[3] = fmaxf(acc[i][7] + p.w + q.w, 0.f);
    }
    __syncthreads();
    if (t < 64) {
        const int c = t;
        float sum = 0.f;
        int runstart = 0;
        for (int m = 0; m < BM; ++m) {
            sum += V[m * SV + c];
            if (m == BM - 1 || dstS[m + 1] != dstS[m]) {
                float* p = m_node + (size_t)dstS[m] * DD + 64 + c;
                if (runstart == 0 || m == BM - 1) atomicAdd(p, sum);
                else *p = sum;
                sum = 0.f; runstart = m + 1;
            }
        }
    }
}

// ---------- T = m_node @ W2^T ------------------------------------------------------
__global__ __launch_bounds__(256, 4)
void t_kernel(const float* __restrict__ m_node, const float* __restrict__ W2,
              float* __restrict__ T)
{
    __shared__ float As[BM * LDA];
    __shared__ float Ws[DD * LDA];
    const int t = threadIdx.x;
    const int n0 = blockIdx.x * BM;
    const int tx = t & 15, ty = t >> 4;

    float acc[8][8];
    #pragma unroll
    for (int i = 0; i < 8; ++i)
        #pragma unroll
        for (int j = 0; j < 8; ++j) acc[i][j] = 0.f;

    for (int kt = 0; kt < 4; ++kt) {
        #pragma unroll
        for (int i = 0; i < 4; ++i) {
            int idx = i * 256 + t, m = idx >> 3, c4 = idx & 7;
            int n = n0 + m; if (n >= NN) n = NN - 1;
            float4 v = *(const float4*)(m_node + (size_t)n * DD + kt * BK + c4 * 4);
            float* w = As + m * LDA + c4 * 4;
            w[0] = v.x; w[1] = v.y; w[2] = v.z; w[3] = v.w;
        }
        #pragma unroll
        for (int i = 0; i < 4; ++i) {
            int idx = i * 256 + t, d = idx >> 3, c4 = idx & 7;
            float4 v = *(const float4*)(W2 + (size_t)d * DD + kt * BK + c4 * 4);
            float* w = Ws + d * LDA + c4 * 4;
            w[0] = v.x; w[1] = v.y; w[2] = v.z; w[3] = v.w;
        }
        __syncthreads();
        #pragma unroll 8
        for (int f = 0; f < BK; ++f) {
            float a[8], b[8];
            #pragma unroll
            for (int i = 0; i < 8; ++i) a[i] = As[(ty * 8 + i) * LDA + f];
            #pragma unroll
            for (int j = 0; j < 4; ++j) {
                b[j]     = Ws[(tx * 4 + j) * LDA + f];
                b[4 + j] = Ws[(64 + tx * 4 + j) * LDA + f];
            }
            #pragma unroll
            for (int i = 0; i < 8; ++i)
                #pragma unroll
                for (int j = 0; j < 8; ++j)
                    acc[i][j] = fmaf(a[i], b[j], acc[i][j]);
        }
        __syncthreads();
    }
    #pragma unroll
    for (int i = 0; i < 8; ++i) {
        int n = n0 + ty * 8 + i;
        if (n < NN) {
            float4 o1 = { acc[i][0], acc[i][1], acc[i][2], acc[i][3] };
            float4 o2 = { acc[i][4], acc[i][5], acc[i][6], acc[i][7] };
            *(float4*)(T + (size_t)n * DD + tx * 4)      = o1;
            *(float4*)(T + (size_t)n * DD + 64 + tx * 4) = o2;
        }
    }
}

// ---------- out = relu(LN(T[src] * snorm_n)) — 32 lanes per edge row ---------------
__global__ __launch_bounds__(256, 8)
void final_kernel(const float* __restrict__ T, const float* __restrict__ snorm_n,
                  const float* __restrict__ gamma, const float* __restrict__ beta,
                  const int* __restrict__ src, float* __restrict__ out)
{
    const int t = threadIdx.x;
    const int l = t & 31;
    const int e = blockIdx.x * 8 + (t >> 5);
    const int s = src[e];
    const float sc = snorm_n[e];
    float4 v = *(const float4*)(T + (size_t)s * DD + l * 4);
    v.x *= sc; v.y *= sc; v.z *= sc; v.w *= sc;
    float sum = v.x + v.y + v.z + v.w;
    float sq  = v.x * v.x + v.y * v.y + v.z * v.z + v.w * v.w;
    #pragma unroll
    for (int off = 1; off < 32; off <<= 1) {
        sum += __shfl_xor(sum, off);
        sq  += __shfl_xor(sq,  off);
    }
    float mu  = sum * (1.f / 128.f);
    float var = sq * (1.f / 128.f) - mu * mu;
    float rs  = rsqrtf(var + 1e-5f);
    float4 g = *(const float4*)(gamma + l * 4);
    float4 b = *(const float4*)(beta  + l * 4);
    float4 o;
    o.x = fmaxf((v.x - mu) * rs * g.x + b.x, 0.f);
    o.y = fmaxf((v.y - mu) * rs * g.y + b.y, 0.f);
    o.z = fmaxf((v.z - mu) * rs * g.z + b.z, 0.f);
    o.w = fmaxf((v.w - mu) * rs * g.w + b.w, 0.f);
    *(float4*)(out + (size_t)e * DD + l * 4) = o;
}

extern "C" void kernel_launch(void* const* d_in, const int* in_sizes, int n_in,
                              void* d_out, int out_size, void* d_ws, size_t ws_size,
                              hipStream_t stream) {
    const float* x       = (const float*)d_in[0];
    const float* h       = (const float*)d_in[1];
    const float* snorm_n = (const float*)d_in[2];
    const float* W1      = (const float*)d_in[4];
    const float* W2      = (const float*)d_in[5];
    const float* gamma   = (const float*)d_in[6];
    const float* beta    = (const float*)d_in[7];
    const int*   src     = (const int*)d_in[8];
    const int*   dst     = (const int*)d_in[9];
    float* out = (float*)d_out;

    const size_t NF = (size_t)NN * DD;       // 5.12M floats per node-array
    float* m_node = (float*)d_ws;            // [0 .. NF)
    float* P      = m_node + NF;
    float* Q      = m_node + 2 * NF;
    float* T      = m_node + 3 * NF;         // 81.9 MB
    int*   deg    = (int*)(m_node + 4 * NF); // NN ints
    int*   cursor = deg + NN;                // NN ints
    int*   eid_s  = cursor + NN;             // NE ints
    int*   dst_s  = eid_s + NE;              // NE ints
    int*   src_s  = dst_s + NE;              // NE ints  (total ws ~= 90 MB)

    hipMemsetAsync(m_node, 0, NF * sizeof(float), stream);
    hipMemsetAsync(deg, 0, NN * sizeof(int), stream);

    hist_kernel<<<NE / 256, 256, 0, stream>>>(dst, deg);
    scan_kernel<<<1, 256, 0, stream>>>(deg, cursor);
    scatter_kernel<<<NE / 256, 256, 0, stream>>>(src, dst, cursor, eid_s, dst_s, src_s);

    pq_kernel<<<dim3(NTILES, 2), 256, 0, stream>>>(x, W1, P, Q);
    r_gemm_seg<<<NE / BM, 256, 0, stream>>>(h, W1, P, Q, eid_s, src_s, dst_s, m_node);
    t_kernel<<<NTILES, 256, 0, stream>>>(m_node, W2, T);
    final_kernel<<<NE / 8, 256, 0, stream>>>(T, snorm_n, gamma, beta, src, out);
}